// Round 4
// baseline (437.691 us; speedup 1.0000x reference)
//
#include <hip/hip_runtime.h>

// MHA forward, MI355X/gfx950.
// B=2, S=2048, D_MODEL=2048, H=16, DK=128. All GEMMs bf16-MFMA (16x16x32),
// fp32 accumulate. Weights are W[e][d] == B^T ("gemm_bt" shape).
//
// Workspace layout (96 MiB):
//   [0,16M)   XB   : x cast to bf16  (later reused as attention output)
//   [16,40M)  WQKV : [WQ;WK;WV] bf16, 6144x2048
//   [40,48M)  WOB  : wo bf16
//   [48,64M)  Q bf16 (token-major; RoPE'd + pre-scaled log2e/sqrt(128) by rope pass)
//   [64,80M)  K bf16 (token-major; RoPE'd)
//   [80,96M)  V^T bf16: [b*2048 + h*128 + d][s]

#define DMODEL 2048
#define SEQ    2048
#define NHEAD  16
#define DKH    128
#define NBATCH 2
#define MTOK   (NBATCH*SEQ)   // 4096

typedef float  f32x4  __attribute__((ext_vector_type(4)));
typedef __bf16 bf16x8 __attribute__((ext_vector_type(8)));
typedef unsigned short      u16;
typedef unsigned short      u16x4 __attribute__((ext_vector_type(4)));

#if __has_builtin(__builtin_amdgcn_exp2f)
#define EXP2F __builtin_amdgcn_exp2f
#else
#define EXP2F exp2f
#endif

__device__ __forceinline__ float b2f(u16 u) {
    union { unsigned i; float f; } x; x.i = ((unsigned)u) << 16; return x.f;
}
__device__ __forceinline__ u16 f2bf(float f) {  // round-to-nearest-even
    union { float f; unsigned i; } x; x.f = f;
    unsigned r = x.i + 0x7fffu + ((x.i >> 16) & 1u);
    return (u16)(r >> 16);
}

// async global->LDS, 16B per lane; LDS dest is wave-uniform base + lane*16
__device__ __forceinline__ void load_lds16(const void* g, void* l) {
    __builtin_amdgcn_global_load_lds(
        (const __attribute__((address_space(1))) void*)g,
        (__attribute__((address_space(3))) void*)l, 16, 0, 0);
}

// counted vmcnt wait; "memory" clobber pins LDS reads on the correct side
#define WAITVM(N) asm volatile("s_waitcnt vmcnt(" #N ")" ::: "memory")

// raw barrier, scheduling-pinned both sides (no vmcnt drain)
#define PIPE_BAR()                                                          \
    do {                                                                    \
        __builtin_amdgcn_sched_barrier(0);                                  \
        __builtin_amdgcn_s_barrier();                                       \
        __builtin_amdgcn_sched_barrier(0);                                  \
        asm volatile("" ::: "memory");                                      \
    } while (0)

// ---------------------------------------------------------------- fused casts
struct CastArgs {
    const float* src[5];
    u16*         dst[5];
    int          n4[5];
};
__global__ void cast_all_kernel(CastArgs a) {
    int j = blockIdx.y;
    int i = blockIdx.x * blockDim.x + threadIdx.x;
    if (i >= a.n4[j]) return;
    float4 f = ((const float4*)a.src[j])[i];
    uint2 o;
    o.x = (unsigned)f2bf(f.x) | ((unsigned)f2bf(f.y) << 16);
    o.y = (unsigned)f2bf(f.z) | ((unsigned)f2bf(f.w) << 16);
    ((uint2*)a.dst[j])[i] = o;
}

// ---------------------------------------------------------------- 2-phase pipelined GEMM
// Round-2 verified config (117 µs QKV / MfmaUtil 38%): 128x256 tile, BK=64,
// ring-3 LDS (144 KiB), 8 waves (2Mx4N) of 64x64, 2 phases/K-tile, counted
// vmcnt(6) once per K-tile (never drained to 0 in the loop).
//
// Phase = { 8x ds_read_b128 (pre-barrier) ; 3x global_load_lds ; s_barrier ;
//           lgkmcnt(0) ; sched_barrier ; setprio(1) ; 16 MFMA ; setprio(0) ;
//           s_barrier }.
// Ring-3 overwrite of slot (t+2)%3 == (t-1)%3 is safe: tile t-1's reads
// completed (lgkmcnt(0)+barrier) before stage(t+2) is issued.
//
// LDS swizzle: row r (stride 128B) stores k-chunk c at c ^ (r&7); inverse
// applied to the GLOBAL source address (global_load_lds writes linearly).
//
// MODE 0: QKV, grid 768. XCD x owns col-tiles [3x,3x+3) (W 3 MiB
//   L2-resident), sweeps rows col-fastest (FETCH evidence: 106 vs 209 MB).
// MODE 1: O-proj, grid 256 (1 block/CU). XCD x owns row-tiles [4x,4x+4).
template<int MODE>
__global__ __launch_bounds__(512, 2) void gemm_pipe(
    const u16* __restrict__ A, const u16* __restrict__ W,
    const float* __restrict__ qb, const float* __restrict__ kb,
    const float* __restrict__ vb,
    u16* __restrict__ QB, u16* __restrict__ KB, u16* __restrict__ VT,
    float* __restrict__ FO)
{
    constexpr int NT = 32;                  // 2048/64 K-tiles

    __shared__ __align__(16) u16 AS[3][128 * 64];   // 3 x 16 KiB
    __shared__ __align__(16) u16 BS[3][256 * 64];   // 3 x 32 KiB

    const int tid  = threadIdx.x;
    const int lane = tid & 63;
    const int w    = tid >> 6;               // 0..7
    const int wm   = w >> 2, wn = w & 3;     // 2 x 4 wave grid
    const int quad = lane >> 4, l16 = lane & 15;

    int row0, col0;
    if constexpr (MODE == 0) {
        int xcd = blockIdx.x & 7, loc = blockIdx.x >> 3;   // loc 0..95
        int rt  = loc / 3, cl = loc - rt * 3;
        row0 = rt * 128;
        col0 = (xcd * 3 + cl) * 256;
    } else {
        int xcd = blockIdx.x & 7, loc = blockIdx.x >> 3;   // loc 0..31
        row0 = (xcd * 4 + (loc & 3)) * 128;
        col0 = (loc >> 2) * 256;
    }

    const int rl = lane >> 3;                  // r & 7
    const int cg = (lane & 7) ^ rl;            // source chunk (inverse swizzle)

    f32x4 acc[4][4] = {};
    bf16x8 af[4], bfr[4];

#define STAGE_A(slot, j, k0)                                                       \
    load_lds16(A + (size_t)(row0 + (j) * 64 + w * 8 + rl) * 2048 + (k0) + cg * 8,  \
               (void*)((slot) + ((j) * 8 + w) * 512))
#define STAGE_B(slot, j, k0)                                                       \
    load_lds16(W + (size_t)(col0 + (j) * 64 + w * 8 + rl) * 2048 + (k0) + cg * 8,  \
               (void*)((slot) + ((j) * 8 + w) * 512))

#define DS_FRAGS(slotA, slotB, ks)                                          \
    {                                                                       \
        _Pragma("unroll") for (int mi = 0; mi < 4; ++mi) {                  \
            int r  = wm * 64 + mi * 16 + l16;                               \
            int cc = ((ks) * 4 + quad) ^ (r & 7);                           \
            af[mi] = *(const bf16x8*)((slotA) + r * 64 + cc * 8);           \
        }                                                                   \
        _Pragma("unroll") for (int ni = 0; ni < 4; ++ni) {                  \
            int r  = wn * 64 + ni * 16 + l16;                               \
            int cc = ((ks) * 4 + quad) ^ (r & 7);                           \
            bfr[ni] = *(const bf16x8*)((slotB) + r * 64 + cc * 8);          \
        }                                                                   \
    }

#define MFMA16()                                                            \
    __builtin_amdgcn_sched_barrier(0);                                      \
    __builtin_amdgcn_s_barrier();                                           \
    asm volatile("s_waitcnt lgkmcnt(0)" ::: "memory");                      \
    __builtin_amdgcn_sched_barrier(0);                                      \
    __builtin_amdgcn_s_setprio(1);                                          \
    _Pragma("unroll") for (int mi = 0; mi < 4; ++mi)                        \
        _Pragma("unroll") for (int ni = 0; ni < 4; ++ni)                    \
            acc[mi][ni] = __builtin_amdgcn_mfma_f32_16x16x32_bf16(          \
                af[mi], bfr[ni], acc[mi][ni], 0, 0, 0);                     \
    __builtin_amdgcn_s_setprio(0);                                          \
    __builtin_amdgcn_sched_barrier(0);                                      \
    __builtin_amdgcn_s_barrier();

    STAGE_A(AS[0], 0, 0);  STAGE_A(AS[0], 1, 0);
    STAGE_B(BS[0], 0, 0);  STAGE_B(BS[0], 1, 0);
    STAGE_B(BS[0], 2, 0);  STAGE_B(BS[0], 3, 0);
    STAGE_A(AS[1], 0, 64); STAGE_A(AS[1], 1, 64);
    STAGE_B(BS[1], 0, 64); STAGE_B(BS[1], 1, 64);
    STAGE_B(BS[1], 2, 64); STAGE_B(BS[1], 3, 64);
    WAITVM(6);
    __builtin_amdgcn_s_barrier();

    int sC = 0, sS = 2;
    for (int t = 0; t < NT - 2; ++t) {
        u16* Ac  = AS[sC]; u16* Bc  = BS[sC];
        u16* Asg = AS[sS]; u16* Bsg = BS[sS];
        const int k0s = (t + 2) * 64;
        DS_FRAGS(Ac, Bc, 0);
        STAGE_A(Asg, 0, k0s); STAGE_A(Asg, 1, k0s); STAGE_B(Bsg, 0, k0s);
        MFMA16();
        DS_FRAGS(Ac, Bc, 1);
        STAGE_B(Bsg, 1, k0s); STAGE_B(Bsg, 2, k0s); STAGE_B(Bsg, 3, k0s);
        WAITVM(6);
        MFMA16();
        sC = (sC == 2) ? 0 : sC + 1;
        sS = (sS == 2) ? 0 : sS + 1;
    }
    {   // t = NT-2
        u16* Ac = AS[sC]; u16* Bc = BS[sC];
        DS_FRAGS(Ac, Bc, 0); MFMA16();
        DS_FRAGS(Ac, Bc, 1); WAITVM(0); MFMA16();
        sC = (sC == 2) ? 0 : sC + 1;
    }
    {   // t = NT-1
        u16* Ac = AS[sC]; u16* Bc = BS[sC];
        DS_FRAGS(Ac, Bc, 0); MFMA16();
        DS_FRAGS(Ac, Bc, 1);
        asm volatile("s_waitcnt lgkmcnt(0)" ::: "memory");
        __builtin_amdgcn_sched_barrier(0);
#pragma unroll
        for (int mi = 0; mi < 4; ++mi)
#pragma unroll
            for (int ni = 0; ni < 4; ++ni)
                acc[mi][ni] = __builtin_amdgcn_mfma_f32_16x16x32_bf16(
                    af[mi], bfr[ni], acc[mi][ni], 0, 0, 0);
    }

    // ---------------- epilogue ----------------
    if constexpr (MODE == 1) {
#pragma unroll
        for (int mi = 0; mi < 4; ++mi) {
#pragma unroll
            for (int ni = 0; ni < 4; ++ni) {
                int col = col0 + wn * 64 + ni * 16 + l16;
                float bv = qb[col];   // wo_b
#pragma unroll
                for (int r = 0; r < 4; ++r) {
                    int row = row0 + wm * 64 + mi * 16 + quad * 4 + r;
                    FO[(size_t)row * DMODEL + col] = acc[mi][ni][r] + bv;
                }
            }
        }
    } else {
        const int sect = col0 >> 11;   // 0=Q, 1=K, 2=V
        if (sect == 2) {
            // V^T epilogue: s consecutive over reg index -> u16x4 store
#pragma unroll
            for (int mi = 0; mi < 4; ++mi) {
#pragma unroll
                for (int ni = 0; ni < 4; ++ni) {
                    int colv = (col0 & 2047) + wn * 64 + ni * 16 + l16;
                    float bv = vb[colv];
                    int rowb = row0 + wm * 64 + mi * 16 + quad * 4;
                    int bb = rowb >> 11, s = rowb & 2047;
                    u16x4 pk;
#pragma unroll
                    for (int r = 0; r < 4; ++r) pk[r] = f2bf(acc[mi][ni][r] + bv);
                    *(u16x4*)(VT + (size_t)(bb * 2048 + colv) * 2048 + s) = pk;
                }
            }
        } else {
            const float* bias = sect ? kb : qb;
            u16* dst          = sect ? KB : QB;
#pragma unroll
            for (int mi = 0; mi < 4; ++mi) {
#pragma unroll
                for (int ni = 0; ni < 4; ++ni) {
                    int col = (col0 & 2047) + wn * 64 + ni * 16 + l16;
                    float bv = bias[col];
#pragma unroll
                    for (int r = 0; r < 4; ++r) {
                        int row = row0 + wm * 64 + mi * 16 + quad * 4 + r;
                        dst[(size_t)row * 2048 + col] = f2bf(acc[mi][ni][r] + bv);
                    }
                }
            }
        }
    }
#undef STAGE_A
#undef STAGE_B
#undef DS_FRAGS
#undef MFMA16
}

// ---------------------------------------------------------------- RoPE (in-place)
// blockIdx.y: 0->Q (folds log2e/sqrt(128) for exp2-domain softmax), 1->K.
__global__ void rope_kernel(u16* __restrict__ Q, u16* __restrict__ Kt) {
    int idx = blockIdx.x * blockDim.x + threadIdx.x;   // < MTOK*NHEAD*64
    u16* P      = blockIdx.y ? Kt : Q;
    float scale = blockIdx.y ? 1.0f : 0.12751743558f;  // log2e/sqrt(128)
    int i   = idx & 63;          // frequency index
    int tok = idx >> 10;         // (h*64+i) packs into 10 bits
    int s   = tok & (SEQ - 1);
    unsigned pr = *(const unsigned*)(P + 2 * (size_t)idx);
    float e = b2f((u16)(pr & 0xffff)), o = b2f((u16)(pr >> 16));
    float inv_freq = exp2f(-13.287712379549449f * (float)i * (1.0f / 64.0f));
    float ang = (float)s * inv_freq;
    float c, sn;
    sincosf(ang, &sn, &c);
    float re = (e * c - o * sn) * scale;
    float ro = (e * sn + o * c) * scale;
    *(unsigned*)(P + 2 * (size_t)idx) = (unsigned)f2bf(re) | ((unsigned)f2bf(ro) << 16);
}

// ---------------------------------------------------------------- flash attention
// Paired-tile blocks (waves 0-3: q-tile p, waves 4-7: q-tile 31-p) sharing
// staged K/V^T. Constant-max exp2 softmax: p = exp2(s - 32); the 2^-32 shift
// is exact and undone by the final 1/l. l-sum reduced across lanes ONCE
// after the K-loop.
//
// Round-4 changes:
//  * T14 async-STAGE split: tile kt+1's K/V loaded global->REGS at the top
//    of iteration kt (latency hidden under QK/PV MFMAs), then ds_written
//    into the single LDS buffer after the barrier that ends tile-kt reads.
//    No global_load_lds, no vmcnt drains; compiler inserts precise waits on
//    register use. Same 50 KB LDS -> 2 blocks/CU co-residency retained.
//  * XCD-locality grid swizzle: id -> (xcd = id&7) owns bh in [4*xcd,4*xcd+4)
//    so each XCD's K/V working set is 4 MiB (= its L2), removing cross-XCD
//    duplicate K/V fetch.
__global__ __launch_bounds__(512, 4) void attn_kernel(
    const u16* __restrict__ Q, const u16* __restrict__ Kg,
    const u16* __restrict__ VTg, u16* __restrict__ Out)
{
    const int id  = blockIdx.x;          // 0..511
    const int kk  = id >> 3;
    const int bh  = (id & 7) * 4 + (kk & 3);
    const int p   = kk >> 2;             // pair index 0..15
    const int b   = bh >> 4, h = bh & 15;

    const int tid  = threadIdx.x;
    const int lane = tid & 63;
    const int w    = tid >> 6;           // 0..7
    const int half = w >> 2;             // 0 = low tile, 1 = high tile
    const int wsub = w & 3;
    const int quad = lane >> 4, l16 = lane & 15;

    const int q_hi  = 31 - p;
    const int my_qt = half ? q_hi : p;
    const int q0    = my_qt * 64;

    __shared__ u16 Ks[64 * 128];         // 16 KB, swizzle ^(r&15)
    __shared__ u16 Vt[128 * 64];         // 16 KB, [d][key], swizzle ^(r&7)
    __shared__ u16 Ps[8][16 * 72];       // 18 KB per-wave P buffers

    bf16x8 qf[4];
    const u16* qrow = Q + (size_t)(b * SEQ + q0 + wsub * 16 + l16) * DMODEL + h * DKH;
#pragma unroll
    for (int ks = 0; ks < 4; ++ks) qf[ks] = *(const bf16x8*)(qrow + ks * 32 + quad * 8);

    // staging addresses (identical layout to the old global_load_lds path):
    // chunk pc = (i*8+w)*64 + lane; K: row r=pc>>4, slot pc&15 holds source
    // chunk (pc&15)^(r&15); V: row r=pc>>3, slot pc&7 holds (pc&7)^(r&7).
    const int pc0 = w * 64 + lane;       // i=0 chunk
    const int pc1 = 512 + pc0;           // i=1 chunk
    const u16* kga[2]; const u16* vga[2];
    {
        int r0 = pc0 >> 4, c0 = (pc0 & 15) ^ (r0 & 15);
        int r1 = pc1 >> 4, c1 = (pc1 & 15) ^ (r1 & 15);
        kga[0] = Kg + (size_t)(b * SEQ + r0) * DMODEL + h * DKH + c0 * 8;
        kga[1] = Kg + (size_t)(b * SEQ + r1) * DMODEL + h * DKH + c1 * 8;
        int s0 = pc0 >> 3, d0 = (pc0 & 7) ^ (s0 & 7);
        int s1 = pc1 >> 3, d1 = (pc1 & 7) ^ (s1 & 7);
        vga[0] = VTg + (size_t)(b * 2048 + h * DKH + s0) * SEQ + d0 * 8;
        vga[1] = VTg + (size_t)(b * 2048 + h * DKH + s1) * SEQ + d1 * 8;
    }
    uint4 kreg[2], vreg[2];

    f32x4 o[8] = {};
    float l_r[4] = { 0.f, 0.f, 0.f, 0.f };   // per-lane partial softmax sums

    // prologue: tile 0 -> regs -> LDS
    kreg[0] = *(const uint4*)(kga[0]); kreg[1] = *(const uint4*)(kga[1]);
    vreg[0] = *(const uint4*)(vga[0]); vreg[1] = *(const uint4*)(vga[1]);
    *(uint4*)(Ks + pc0 * 8) = kreg[0]; *(uint4*)(Ks + pc1 * 8) = kreg[1];
    *(uint4*)(Vt + pc0 * 8) = vreg[0]; *(uint4*)(Vt + pc1 * 8) = vreg[1];
    PIPE_BAR();

    for (int kt = 0; kt <= q_hi; ++kt) {
        // ---- issue next tile's loads into regs (overlap with compute)
        if (kt < q_hi) {
            const int k1 = (kt + 1) * 64;
            kreg[0] = *(const uint4*)(kga[0] + k1 * DMODEL);
            kreg[1] = *(const uint4*)(kga[1] + k1 * DMODEL);
            vreg[0] = *(const uint4*)(vga[0] + k1);
            vreg[1] = *(const uint4*)(vga[1] + k1);
        }

        if (kt <= my_qt) {
            const int k0 = kt * 64;
            // ---- S = Q K^T  (exp2-domain: log2e*scale folded into Q)
            f32x4 sc[4] = {};
#pragma unroll
            for (int ks = 0; ks < 4; ++ks) {
#pragma unroll
                for (int nt = 0; nt < 4; ++nt) {
                    int r  = nt * 16 + l16;
                    int pc = (ks * 4 + quad) ^ (r & 15);
                    bf16x8 kf = *(const bf16x8*)(Ks + (r * 16 + pc) * 8);
                    sc[nt] = __builtin_amdgcn_mfma_f32_16x16x32_bf16(qf[ks], kf, sc[nt], 0, 0, 0);
                }
            }
            if (kt == my_qt) {
#pragma unroll
                for (int nt = 0; nt < 4; ++nt)
#pragma unroll
                    for (int r = 0; r < 4; ++r) {
                        int col = k0 + nt * 16 + l16;
                        int row = q0 + wsub * 16 + quad * 4 + r;
                        if (col > row) sc[nt][r] = -1e30f;
                    }
            }
            // ---- p = exp2(s - 32); accumulate per-lane l; store P to LDS
#pragma unroll
            for (int nt = 0; nt < 4; ++nt)
#pragma unroll
                for (int r = 0; r < 4; ++r) {
                    float pv = EXP2F(sc[nt][r] - 32.0f);
                    l_r[r] += pv;
                    Ps[w][(quad * 4 + r) * 72 + nt * 16 + l16] = f2bf(pv);
                }
            // ---- O += P V  (same-wave LDS write->read; no barrier needed)
#pragma unroll
            for (int ks = 0; ks < 2; ++ks) {
                bf16x8 pf = *(const bf16x8*)(&Ps[w][l16 * 72 + ks * 32 + quad * 8]);
#pragma unroll
                for (int nt = 0; nt < 8; ++nt) {
                    int r  = nt * 16 + l16;                  // d
                    int pc = (ks * 4 + quad) ^ (r & 7);
                    bf16x8 vf = *(const bf16x8*)(Vt + r * 64 + pc * 8);
                    o[nt] = __builtin_amdgcn_mfma_f32_16x16x32_bf16(pf, vf, o[nt], 0, 0, 0);
                }
            }
        }

        PIPE_BAR();                       // all reads of tile kt complete
        if (kt < q_hi) {                  // overwrite with tile kt+1
            *(uint4*)(Ks + pc0 * 8) = kreg[0]; *(uint4*)(Ks + pc1 * 8) = kreg[1];
            *(uint4*)(Vt + pc0 * 8) = vreg[0]; *(uint4*)(Vt + pc1 * 8) = vreg[1];
        }
        PIPE_BAR();                       // writes visible to all waves
    }

    // ---- one l-reduction across the 16 lanes of each quad, then store
#pragma unroll
    for (int r = 0; r < 4; ++r) {
#pragma unroll
        for (int off = 1; off < 16; off <<= 1) l_r[r] += __shfl_xor(l_r[r], off);
        float inv = 1.0f / l_r[r];
        int row = q0 + wsub * 16 + quad * 4 + r;
#pragma unroll
        for (int nt = 0; nt < 8; ++nt)
            Out[(size_t)(b * SEQ + row) * DMODEL + h * DKH + nt * 16 + l16] = f2bf(o[nt][r] * inv);
    }
}

// ---------------------------------------------------------------- launch
extern "C" void kernel_launch(void* const* d_in, const int* in_sizes, int n_in,
                              void* d_out, int out_size, void* d_ws, size_t ws_size,
                              hipStream_t stream)
{
    const float* x    = (const float*)d_in[0];
    const float* wq_w = (const float*)d_in[1];
    const float* wq_b = (const float*)d_in[2];
    const float* wk_w = (const float*)d_in[3];
    const float* wk_b = (const float*)d_in[4];
    const float* wv_w = (const float*)d_in[5];
    const float* wv_b = (const float*)d_in[6];
    const float* wo_w = (const float*)d_in[7];
    const float* wo_b = (const float*)d_in[8];
    float* out = (float*)d_out;

    char* ws = (char*)d_ws;
    u16* XB   = (u16*)(ws);                     // 16 MiB, reused as attn output
    u16* WQKV = (u16*)(ws + (16u << 20));       // 24 MiB
    u16* WOB  = (u16*)(ws + (40u << 20));       // 8 MiB
    u16* QB   = (u16*)(ws + (48u << 20));
    u16* KB   = (u16*)(ws + (64u << 20));
    u16* VTB  = (u16*)(ws + (80u << 20));       // V^T: [b*2048+h*128+d][s]

    CastArgs ca;
    ca.src[0] = x;    ca.dst[0] = XB;                         ca.n4[0] = (MTOK * DMODEL) / 4;
    ca.src[1] = wq_w; ca.dst[1] = WQKV;                       ca.n4[1] = (DMODEL * DMODEL) / 4;
    ca.src[2] = wk_w; ca.dst[2] = WQKV + DMODEL * DMODEL;     ca.n4[2] = (DMODEL * DMODEL) / 4;
    ca.src[3] = wv_w; ca.dst[3] = WQKV + 2 * DMODEL * DMODEL; ca.n4[3] = (DMODEL * DMODEL) / 4;
    ca.src[4] = wo_w; ca.dst[4] = WOB;                        ca.n4[4] = (DMODEL * DMODEL) / 4;
    cast_all_kernel<<<dim3(8192, 5), 256, 0, stream>>>(ca);

    // QKV: 32 row-tiles x 24 col-tiles = 768 blocks (3 full CU rounds)
    gemm_pipe<0><<<dim3(768), 512, 0, stream>>>(
        XB, WQKV, wq_b, wk_b, wv_b, QB, KB, VTB, nullptr);

    rope_kernel<<<dim3((MTOK * NHEAD * 64) / 256, 2), 256, 0, stream>>>(QB, KB);

    // attn: 512 blocks, XCD-locality swizzled (4 heads per XCD = 4 MiB K/V)
    attn_kernel<<<dim3(512), 512, 0, stream>>>(QB, KB, VTB, XB);

    // O-proj: 32 x 8 = 256 blocks (exactly 1/CU)
    gemm_pipe<1><<<dim3(256), 512, 0, stream>>>(
        XB, WOB, wo_b, nullptr, nullptr, nullptr, nullptr, nullptr, out);
}

// Round 5
// 410.479 us; speedup vs baseline: 1.0663x; 1.0663x over previous
//
#include <hip/hip_runtime.h>

// MHA forward, MI355X/gfx950.
// B=2, S=2048, D_MODEL=2048, H=16, DK=128. All GEMMs bf16-MFMA (16x16x32),
// fp32 accumulate. Weights are W[e][d] == B^T ("gemm_bt" shape).
//
// Workspace layout (96 MiB):
//   [0,16M)   XB   : x cast to bf16  (later reused as attention output)
//   [16,40M)  WQKV : [WQ;WK;WV] bf16, 6144x2048
//   [40,48M)  WOB  : wo bf16
//   [48,64M)  Q bf16 (token-major; RoPE'd + pre-scaled log2e/sqrt(128) by rope pass)
//   [64,80M)  K bf16 (token-major; RoPE'd)
//   [80,96M)  V^T bf16: [b*2048 + h*128 + d][s]

#define DMODEL 2048
#define SEQ    2048
#define NHEAD  16
#define DKH    128
#define NBATCH 2
#define MTOK   (NBATCH*SEQ)   // 4096

typedef float  f32x4  __attribute__((ext_vector_type(4)));
typedef __bf16 bf16x8 __attribute__((ext_vector_type(8)));
typedef unsigned short      u16;
typedef unsigned short      u16x4 __attribute__((ext_vector_type(4)));

#if __has_builtin(__builtin_amdgcn_exp2f)
#define EXP2F __builtin_amdgcn_exp2f
#else
#define EXP2F exp2f
#endif

__device__ __forceinline__ float b2f(u16 u) {
    union { unsigned i; float f; } x; x.i = ((unsigned)u) << 16; return x.f;
}
__device__ __forceinline__ u16 f2bf(float f) {  // round-to-nearest-even
    union { float f; unsigned i; } x; x.f = f;
    unsigned r = x.i + 0x7fffu + ((x.i >> 16) & 1u);
    return (u16)(r >> 16);
}

// async global->LDS, 16B per lane; LDS dest is wave-uniform base + lane*16
__device__ __forceinline__ void load_lds16(const void* g, void* l) {
    __builtin_amdgcn_global_load_lds(
        (const __attribute__((address_space(1))) void*)g,
        (__attribute__((address_space(3))) void*)l, 16, 0, 0);
}

// counted vmcnt wait; "memory" clobber pins LDS reads on the correct side
#define WAITVM(N) asm volatile("s_waitcnt vmcnt(" #N ")" ::: "memory")

// ---------------------------------------------------------------- fused casts
struct CastArgs {
    const float* src[5];
    u16*         dst[5];
    int          n4[5];
};
__global__ void cast_all_kernel(CastArgs a) {
    int j = blockIdx.y;
    int i = blockIdx.x * blockDim.x + threadIdx.x;
    if (i >= a.n4[j]) return;
    float4 f = ((const float4*)a.src[j])[i];
    uint2 o;
    o.x = (unsigned)f2bf(f.x) | ((unsigned)f2bf(f.y) << 16);
    o.y = (unsigned)f2bf(f.z) | ((unsigned)f2bf(f.w) << 16);
    ((uint2*)a.dst[j])[i] = o;
}

// ---------------------------------------------------------------- QKV GEMM (256x256, ring-2)
// C[4096][6144] = X[4096][2048] * WQKV[6144][2048]^T + bias.
// 256x256 tile, BK=64, ring-2 LDS (128 KiB), 8 waves (2Mx4N) each owning
// 128x64 (acc 8x4, 43.7 MFMA-FLOP per ds-byte vs 32 for 64x64 waves).
//
// Pipeline (round-2 proven sync skeleton at tile grain):
//   tile top : issue ALL 8 stage loads for tile t+1 into slot (t+1)&1
//   4 phases : {ds_read frags ; SBAR ; lgkm0 ; setprio1 ; 16 MFMA ;
//               setprio0 ; SBAR}   (phases: (mh0,ks0)(mh1,ks0)(mh0,ks1)(mh1,ks1))
//   boundary : WAITVM(0) — waits on loads issued 4 phases (~1000 cyc)
//              earlier, so the drain is short — then SBAR.
// Slot (t+1)&1 overwrite is safe: tile t-1's ds_reads all completed before
// its closing SBAR, and stage(t+1) is issued only after passing it.
//
// LDS swizzle identical to round-2 (proven 0-conflict): row r (128B stride)
// stores k-chunk c at c ^ (r&7); inverse applied to the GLOBAL source
// address (global_load_lds writes linearly).
//
// Grid 384 = 8 XCD x (16 rows x 3 cols), col-fastest within XCD (W 3 MiB
// L2-resident per XCD; FETCH evidence r2/r3: 106/94 MB vs 209 row-fastest).
__global__ __launch_bounds__(512, 2) void gemm_qkv256(
    const u16* __restrict__ A, const u16* __restrict__ W,
    const float* __restrict__ qb, const float* __restrict__ kb,
    const float* __restrict__ vb,
    u16* __restrict__ QB, u16* __restrict__ KB, u16* __restrict__ VT)
{
    __shared__ __align__(16) u16 AS[2][256 * 64];   // 2 x 32 KiB
    __shared__ __align__(16) u16 BS[2][256 * 64];   // 2 x 32 KiB

    const int tid  = threadIdx.x;
    const int lane = tid & 63;
    const int w    = tid >> 6;               // 0..7
    const int wm   = w >> 2, wn = w & 3;     // 2 x 4 wave grid, wave = 128x64
    const int quad = lane >> 4, l16 = lane & 15;

    const int xcd = blockIdx.x & 7, loc = blockIdx.x >> 3;   // loc 0..47
    const int rt  = loc / 3, cl = loc - rt * 3;
    const int row0 = rt * 256;
    const int col0 = (xcd * 3 + cl) * 256;

    const int rl = lane >> 3;                  // staging row low bits
    const int cg = (lane & 7) ^ rl;            // source chunk (inverse swizzle)

    f32x4 acc[8][4] = {};
    bf16x8 af[4], bfr[4];

#define STG(dst, src, b0, j, k0)                                                   \
    load_lds16(src + (size_t)((b0) + (j) * 64 + w * 8 + rl) * 2048 + (k0) + cg * 8,\
               (void*)((dst) + ((j) * 8 + w) * 512))
#define STAGE_TILE(t) {                                                            \
    const int k0_ = (t) * 64;                                                      \
    u16* As_ = AS[(t) & 1]; u16* Bs_ = BS[(t) & 1];                                \
    STG(As_, A, row0, 0, k0_); STG(As_, A, row0, 1, k0_);                          \
    STG(As_, A, row0, 2, k0_); STG(As_, A, row0, 3, k0_);                          \
    STG(Bs_, W, col0, 0, k0_); STG(Bs_, W, col0, 1, k0_);                          \
    STG(Bs_, W, col0, 2, k0_); STG(Bs_, W, col0, 3, k0_); }

#define QDS_A(Sl, mh, ks) _Pragma("unroll") for (int mi = 0; mi < 4; ++mi) {       \
        int ra = wm * 128 + (mh) * 64 + mi * 16 + l16;                             \
        int cc = ((ks) * 4 + quad) ^ (ra & 7);                                     \
        af[mi] = *(const bf16x8*)((Sl) + ra * 64 + cc * 8); }
#define QDS_B(Sl, ks) _Pragma("unroll") for (int ni = 0; ni < 4; ++ni) {           \
        int rb = wn * 64 + ni * 16 + l16;                                          \
        int cc = ((ks) * 4 + quad) ^ (rb & 7);                                     \
        bfr[ni] = *(const bf16x8*)((Sl) + rb * 64 + cc * 8); }

// phase core: align waves, drain ds_reads, clustered MFMA (no closing bar)
#define QPHASE(mh)                                                                 \
    __builtin_amdgcn_sched_barrier(0);                                             \
    __builtin_amdgcn_s_barrier();                                                  \
    asm volatile("s_waitcnt lgkmcnt(0)" ::: "memory");                             \
    __builtin_amdgcn_sched_barrier(0);                                             \
    __builtin_amdgcn_s_setprio(1);                                                 \
    _Pragma("unroll") for (int mi = 0; mi < 4; ++mi)                               \
    _Pragma("unroll") for (int ni = 0; ni < 4; ++ni)                               \
        acc[(mh) * 4 + mi][ni] = __builtin_amdgcn_mfma_f32_16x16x32_bf16(          \
            af[mi], bfr[ni], acc[(mh) * 4 + mi][ni], 0, 0, 0);                     \
    __builtin_amdgcn_s_setprio(0);                                                 \
    __builtin_amdgcn_sched_barrier(0);

    // prologue: tile 0 staged and landed
    STAGE_TILE(0);
    WAITVM(0);
    __builtin_amdgcn_s_barrier();

    for (int t = 0; t < 32; ++t) {
        const u16* Asl = AS[t & 1];
        const u16* Bsl = BS[t & 1];
        if (t < 31) STAGE_TILE(t + 1);           // 8 loads, land by boundary
        QDS_A(Asl, 0, 0); QDS_B(Bsl, 0);
        QPHASE(0); __builtin_amdgcn_s_barrier();
        QDS_A(Asl, 1, 0);
        QPHASE(1); __builtin_amdgcn_s_barrier();
        QDS_A(Asl, 0, 1); QDS_B(Bsl, 1);
        QPHASE(0); __builtin_amdgcn_s_barrier();
        QDS_A(Asl, 1, 1);
        QPHASE(1);
        if (t < 31) { WAITVM(0); }               // tile t+1 landed (per-wave)
        __builtin_amdgcn_s_barrier();            // boundary: landed chip-wide
    }
#undef STG
#undef STAGE_TILE
#undef QDS_A
#undef QDS_B
#undef QPHASE

    // ---------------- epilogue ----------------
    const int sect = col0 >> 11;   // 0=Q, 1=K, 2=V
    if (sect == 2) {
        // V^T epilogue: s consecutive over reg index -> u16x4 store
#pragma unroll
        for (int mi = 0; mi < 8; ++mi) {
#pragma unroll
            for (int ni = 0; ni < 4; ++ni) {
                int colv = (col0 & 2047) + wn * 64 + ni * 16 + l16;
                float bv = vb[colv];
                int rowb = row0 + wm * 128 + mi * 16 + quad * 4;
                int bb = rowb >> 11, s = rowb & 2047;
                u16x4 pk;
#pragma unroll
                for (int r = 0; r < 4; ++r) pk[r] = f2bf(acc[mi][ni][r] + bv);
                *(u16x4*)(VT + (size_t)(bb * 2048 + colv) * 2048 + s) = pk;
            }
        }
    } else {
        const float* bias = sect ? kb : qb;
        u16* dst          = sect ? KB : QB;
#pragma unroll
        for (int mi = 0; mi < 8; ++mi) {
#pragma unroll
            for (int ni = 0; ni < 4; ++ni) {
                int col = (col0 & 2047) + wn * 64 + ni * 16 + l16;
                float bv = bias[col];
#pragma unroll
                for (int r = 0; r < 4; ++r) {
                    int row = row0 + wm * 128 + mi * 16 + quad * 4 + r;
                    dst[(size_t)row * 2048 + col] = f2bf(acc[mi][ni][r] + bv);
                }
            }
        }
    }
}

// ---------------------------------------------------------------- O-proj GEMM
// Round-2 proven config: 128x256 tile, BK=64, ring-3 LDS (144 KiB), 8 waves
// (2x4) of 64x64, 2 phases/K-tile, counted vmcnt(6). Grid 256 = 1 block/CU.
__global__ __launch_bounds__(512, 2) void gemm_o_pipe(
    const u16* __restrict__ A, const u16* __restrict__ W,
    const float* __restrict__ bias, float* __restrict__ FO)
{
    constexpr int NT = 32;                  // 2048/64 K-tiles

    __shared__ __align__(16) u16 AS[3][128 * 64];   // 3 x 16 KiB
    __shared__ __align__(16) u16 BS[3][256 * 64];   // 3 x 32 KiB

    const int tid  = threadIdx.x;
    const int lane = tid & 63;
    const int w    = tid >> 6;               // 0..7
    const int wm   = w >> 2, wn = w & 3;     // 2 x 4 wave grid
    const int quad = lane >> 4, l16 = lane & 15;

    const int xcd = blockIdx.x & 7, loc = blockIdx.x >> 3;   // loc 0..31
    const int row0 = (xcd * 4 + (loc & 3)) * 128;
    const int col0 = (loc >> 2) * 256;

    const int rl = lane >> 3;                  // r & 7
    const int cg = (lane & 7) ^ rl;            // source chunk (inverse swizzle)

    f32x4 acc[4][4] = {};
    bf16x8 af[4], bfr[4];

#define STAGE_A(slot, j, k0)                                                       \
    load_lds16(A + (size_t)(row0 + (j) * 64 + w * 8 + rl) * 2048 + (k0) + cg * 8,  \
               (void*)((slot) + ((j) * 8 + w) * 512))
#define STAGE_B(slot, j, k0)                                                       \
    load_lds16(W + (size_t)(col0 + (j) * 64 + w * 8 + rl) * 2048 + (k0) + cg * 8,  \
               (void*)((slot) + ((j) * 8 + w) * 512))

#define DS_FRAGS(slotA, slotB, ks)                                          \
    {                                                                       \
        _Pragma("unroll") for (int mi = 0; mi < 4; ++mi) {                  \
            int r  = wm * 64 + mi * 16 + l16;                               \
            int cc = ((ks) * 4 + quad) ^ (r & 7);                           \
            af[mi] = *(const bf16x8*)((slotA) + r * 64 + cc * 8);           \
        }                                                                   \
        _Pragma("unroll") for (int ni = 0; ni < 4; ++ni) {                  \
            int r  = wn * 64 + ni * 16 + l16;                               \
            int cc = ((ks) * 4 + quad) ^ (r & 7);                           \
            bfr[ni] = *(const bf16x8*)((slotB) + r * 64 + cc * 8);          \
        }                                                                   \
    }

#define MFMA16()                                                            \
    __builtin_amdgcn_sched_barrier(0);                                      \
    __builtin_amdgcn_s_barrier();                                           \
    asm volatile("s_waitcnt lgkmcnt(0)" ::: "memory");                      \
    __builtin_amdgcn_sched_barrier(0);                                      \
    __builtin_amdgcn_s_setprio(1);                                          \
    _Pragma("unroll") for (int mi = 0; mi < 4; ++mi)                        \
        _Pragma("unroll") for (int ni = 0; ni < 4; ++ni)                    \
            acc[mi][ni] = __builtin_amdgcn_mfma_f32_16x16x32_bf16(          \
                af[mi], bfr[ni], acc[mi][ni], 0, 0, 0);                     \
    __builtin_amdgcn_s_setprio(0);                                          \
    __builtin_amdgcn_sched_barrier(0);                                      \
    __builtin_amdgcn_s_barrier();

    STAGE_A(AS[0], 0, 0);  STAGE_A(AS[0], 1, 0);
    STAGE_B(BS[0], 0, 0);  STAGE_B(BS[0], 1, 0);
    STAGE_B(BS[0], 2, 0);  STAGE_B(BS[0], 3, 0);
    STAGE_A(AS[1], 0, 64); STAGE_A(AS[1], 1, 64);
    STAGE_B(BS[1], 0, 64); STAGE_B(BS[1], 1, 64);
    STAGE_B(BS[1], 2, 64); STAGE_B(BS[1], 3, 64);
    WAITVM(6);
    __builtin_amdgcn_s_barrier();

    int sC = 0, sS = 2;
    for (int t = 0; t < NT - 2; ++t) {
        u16* Ac  = AS[sC]; u16* Bc  = BS[sC];
        u16* Asg = AS[sS]; u16* Bsg = BS[sS];
        const int k0s = (t + 2) * 64;
        DS_FRAGS(Ac, Bc, 0);
        STAGE_A(Asg, 0, k0s); STAGE_A(Asg, 1, k0s); STAGE_B(Bsg, 0, k0s);
        MFMA16();
        DS_FRAGS(Ac, Bc, 1);
        STAGE_B(Bsg, 1, k0s); STAGE_B(Bsg, 2, k0s); STAGE_B(Bsg, 3, k0s);
        WAITVM(6);
        MFMA16();
        sC = (sC == 2) ? 0 : sC + 1;
        sS = (sS == 2) ? 0 : sS + 1;
    }
    {   // t = NT-2
        u16* Ac = AS[sC]; u16* Bc = BS[sC];
        DS_FRAGS(Ac, Bc, 0); MFMA16();
        DS_FRAGS(Ac, Bc, 1); WAITVM(0); MFMA16();
        sC = (sC == 2) ? 0 : sC + 1;
    }
    {   // t = NT-1
        u16* Ac = AS[sC]; u16* Bc = BS[sC];
        DS_FRAGS(Ac, Bc, 0); MFMA16();
        DS_FRAGS(Ac, Bc, 1);
        asm volatile("s_waitcnt lgkmcnt(0)" ::: "memory");
        __builtin_amdgcn_sched_barrier(0);
#pragma unroll
        for (int mi = 0; mi < 4; ++mi)
#pragma unroll
            for (int ni = 0; ni < 4; ++ni)
                acc[mi][ni] = __builtin_amdgcn_mfma_f32_16x16x32_bf16(
                    af[mi], bfr[ni], acc[mi][ni], 0, 0, 0);
    }

#pragma unroll
    for (int mi = 0; mi < 4; ++mi) {
#pragma unroll
        for (int ni = 0; ni < 4; ++ni) {
            int col = col0 + wn * 64 + ni * 16 + l16;
            float bv = bias[col];
#pragma unroll
            for (int r = 0; r < 4; ++r) {
                int row = row0 + wm * 64 + mi * 16 + quad * 4 + r;
                FO[(size_t)row * DMODEL + col] = acc[mi][ni][r] + bv;
            }
        }
    }
#undef STAGE_A
#undef STAGE_B
#undef DS_FRAGS
#undef MFMA16
}

// ---------------------------------------------------------------- RoPE (in-place)
// blockIdx.y: 0->Q (folds log2e/sqrt(128) for exp2-domain softmax), 1->K.
__global__ void rope_kernel(u16* __restrict__ Q, u16* __restrict__ Kt) {
    int idx = blockIdx.x * blockDim.x + threadIdx.x;   // < MTOK*NHEAD*64
    u16* P      = blockIdx.y ? Kt : Q;
    float scale = blockIdx.y ? 1.0f : 0.12751743558f;  // log2e/sqrt(128)
    int i   = idx & 63;          // frequency index
    int tok = idx >> 10;         // (h*64+i) packs into 10 bits
    int s   = tok & (SEQ - 1);
    unsigned pr = *(const unsigned*)(P + 2 * (size_t)idx);
    float e = b2f((u16)(pr & 0xffff)), o = b2f((u16)(pr >> 16));
    float inv_freq = exp2f(-13.287712379549449f * (float)i * (1.0f / 64.0f));
    float ang = (float)s * inv_freq;
    float c, sn;
    sincosf(ang, &sn, &c);
    float re = (e * c - o * sn) * scale;
    float ro = (e * sn + o * c) * scale;
    *(unsigned*)(P + 2 * (size_t)idx) = (unsigned)f2bf(re) | ((unsigned)f2bf(ro) << 16);
}

// ---------------------------------------------------------------- flash attention
// Round-0/2 proven version (reverted from round-4 reg-staging experiment,
// which was latency-bound: MfmaUtil 9.7%, 540K LDS write conflicts).
// Paired-tile blocks (waves 0-3: q-tile p, waves 4-7: q-tile 31-p) sharing
// staged K/V^T. Constant-max exp2 softmax: p = exp2(s - 32); the 2^-32 shift
// is exact and undone by the final 1/l. l-sum reduced once after the K-loop.
__global__ __launch_bounds__(512, 4) void attn_kernel(
    const u16* __restrict__ Q, const u16* __restrict__ Kg,
    const u16* __restrict__ VTg, u16* __restrict__ Out)
{
    const int p  = blockIdx.x;           // pair index 0..15
    const int bh = blockIdx.y;
    const int b  = bh >> 4, h = bh & 15;

    const int tid  = threadIdx.x;
    const int lane = tid & 63;
    const int w    = tid >> 6;           // 0..7
    const int half = w >> 2;             // 0 = low tile, 1 = high tile
    const int wsub = w & 3;
    const int quad = lane >> 4, l16 = lane & 15;

    const int q_hi  = 31 - p;
    const int my_qt = half ? q_hi : p;
    const int q0    = my_qt * 64;

    __shared__ u16 Ks[64 * 128];         // 16 KB, swizzle ^(r&15)
    __shared__ u16 Vt[128 * 64];         // 16 KB, [d][key], swizzle ^(r&7)
    __shared__ u16 Ps[8][16 * 72];       // 18 KB per-wave P buffers

    bf16x8 qf[4];
    const u16* qrow = Q + (size_t)(b * SEQ + q0 + wsub * 16 + l16) * DMODEL + h * DKH;
#pragma unroll
    for (int ks = 0; ks < 4; ++ks) qf[ks] = *(const bf16x8*)(qrow + ks * 32 + quad * 8);

    f32x4 o[8] = {};
    float l_r[4] = { 0.f, 0.f, 0.f, 0.f };   // per-lane partial softmax sums

    for (int kt = 0; kt <= q_hi; ++kt) {
        const int k0 = kt * 64;
        // ---- stage K (1024 chunks, 512 threads -> 2 each)
#pragma unroll
        for (int i = 0; i < 2; ++i) {
            int cb = (i * 8 + w) * 64;
            int pc = cb + lane;
            int r  = pc >> 4;
            int cl = (pc & 15) ^ (r & 15);
            load_lds16(Kg + (size_t)(b * SEQ + k0 + r) * DMODEL + h * DKH + cl * 8,
                       (void*)(Ks + cb * 8));
        }
        // ---- stage V^T
#pragma unroll
        for (int i = 0; i < 2; ++i) {
            int cb = (i * 8 + w) * 64;
            int pc = cb + lane;
            int r  = pc >> 3;                 // d
            int cl = (pc & 7) ^ (r & 7);
            load_lds16(VTg + (size_t)(b * 2048 + h * DKH + r) * SEQ + k0 + cl * 8,
                       (void*)(Vt + cb * 8));
        }
        __syncthreads();

        if (kt <= my_qt) {
            // ---- S = Q K^T  (exp2-domain: log2e*scale folded into Q)
            f32x4 sc[4] = {};
#pragma unroll
            for (int ks = 0; ks < 4; ++ks) {
#pragma unroll
                for (int nt = 0; nt < 4; ++nt) {
                    int r  = nt * 16 + l16;
                    int pc = (ks * 4 + quad) ^ (r & 15);
                    bf16x8 kf = *(const bf16x8*)(Ks + (r * 16 + pc) * 8);
                    sc[nt] = __builtin_amdgcn_mfma_f32_16x16x32_bf16(qf[ks], kf, sc[nt], 0, 0, 0);
                }
            }
            if (kt == my_qt) {
#pragma unroll
                for (int nt = 0; nt < 4; ++nt)
#pragma unroll
                    for (int r = 0; r < 4; ++r) {
                        int col = k0 + nt * 16 + l16;
                        int row = q0 + wsub * 16 + quad * 4 + r;
                        if (col > row) sc[nt][r] = -1e30f;
                    }
            }
            // ---- p = exp2(s - 32); accumulate per-lane l; store P to LDS
#pragma unroll
            for (int nt = 0; nt < 4; ++nt)
#pragma unroll
                for (int r = 0; r < 4; ++r) {
                    float pv = EXP2F(sc[nt][r] - 32.0f);
                    l_r[r] += pv;
                    Ps[w][(quad * 4 + r) * 72 + nt * 16 + l16] = f2bf(pv);
                }
            // ---- O += P V  (same-wave LDS write->read; no barrier needed)
#pragma unroll
            for (int ks = 0; ks < 2; ++ks) {
                bf16x8 pf = *(const bf16x8*)(&Ps[w][l16 * 72 + ks * 32 + quad * 8]);
#pragma unroll
                for (int nt = 0; nt < 8; ++nt) {
                    int r  = nt * 16 + l16;                  // d
                    int pc = (ks * 4 + quad) ^ (r & 7);
                    bf16x8 vf = *(const bf16x8*)(Vt + r * 64 + pc * 8);
                    o[nt] = __builtin_amdgcn_mfma_f32_16x16x32_bf16(pf, vf, o[nt], 0, 0, 0);
                }
            }
        }
        __syncthreads();
    }

    // ---- one l-reduction across the 16 lanes of each quad, then store
#pragma unroll
    for (int r = 0; r < 4; ++r) {
#pragma unroll
        for (int off = 1; off < 16; off <<= 1) l_r[r] += __shfl_xor(l_r[r], off);
        float inv = 1.0f / l_r[r];
        int row = q0 + wsub * 16 + quad * 4 + r;
#pragma unroll
        for (int nt = 0; nt < 8; ++nt)
            Out[(size_t)(b * SEQ + row) * DMODEL + h * DKH + nt * 16 + l16] = f2bf(o[nt][r] * inv);
    }
}

// ---------------------------------------------------------------- launch
extern "C" void kernel_launch(void* const* d_in, const int* in_sizes, int n_in,
                              void* d_out, int out_size, void* d_ws, size_t ws_size,
                              hipStream_t stream)
{
    const float* x    = (const float*)d_in[0];
    const float* wq_w = (const float*)d_in[1];
    const float* wq_b = (const float*)d_in[2];
    const float* wk_w = (const float*)d_in[3];
    const float* wk_b = (const float*)d_in[4];
    const float* wv_w = (const float*)d_in[5];
    const float* wv_b = (const float*)d_in[6];
    const float* wo_w = (const float*)d_in[7];
    const float* wo_b = (const float*)d_in[8];
    float* out = (float*)d_out;

    char* ws = (char*)d_ws;
    u16* XB   = (u16*)(ws);                     // 16 MiB, reused as attn output
    u16* WQKV = (u16*)(ws + (16u << 20));       // 24 MiB
    u16* WOB  = (u16*)(ws + (40u << 20));       // 8 MiB
    u16* QB   = (u16*)(ws + (48u << 20));
    u16* KB   = (u16*)(ws + (64u << 20));
    u16* VTB  = (u16*)(ws + (80u << 20));       // V^T: [b*2048+h*128+d][s]

    CastArgs ca;
    ca.src[0] = x;    ca.dst[0] = XB;                         ca.n4[0] = (MTOK * DMODEL) / 4;
    ca.src[1] = wq_w; ca.dst[1] = WQKV;                       ca.n4[1] = (DMODEL * DMODEL) / 4;
    ca.src[2] = wk_w; ca.dst[2] = WQKV + DMODEL * DMODEL;     ca.n4[2] = (DMODEL * DMODEL) / 4;
    ca.src[3] = wv_w; ca.dst[3] = WQKV + 2 * DMODEL * DMODEL; ca.n4[3] = (DMODEL * DMODEL) / 4;
    ca.src[4] = wo_w; ca.dst[4] = WOB;                        ca.n4[4] = (DMODEL * DMODEL) / 4;
    cast_all_kernel<<<dim3(8192, 5), 256, 0, stream>>>(ca);

    // QKV: 16 row-tiles x 24 col-tiles = 384 blocks (256x256 tiles)
    gemm_qkv256<<<dim3(384), 512, 0, stream>>>(
        XB, WQKV, wq_b, wk_b, wv_b, QB, KB, VTB);

    rope_kernel<<<dim3((MTOK * NHEAD * 64) / 256, 2), 256, 0, stream>>>(QB, KB);

    attn_kernel<<<dim3(16, NBATCH * NHEAD), 512, 0, stream>>>(QB, KB, VTB, XB);

    // O-proj: 32 x 8 = 256 blocks (exactly 1/CU)
    gemm_o_pipe<<<dim3(256), 512, 0, stream>>>(XB, WOB, wo_b, out);
}

// Round 6
// 361.310 us; speedup vs baseline: 1.2114x; 1.1361x over previous
//
#include <hip/hip_runtime.h>

// MHA forward, MI355X/gfx950.
// B=2, S=2048, D_MODEL=2048, H=16, DK=128. All GEMMs bf16-MFMA (16x16x32),
// fp32 accumulate. Weights are W[e][d] == B^T ("gemm_bt" shape).
//
// Workspace layout (96 MiB):
//   [0,16M)   XB   : x cast to bf16  (later reused as attention output)
//   [16,40M)  WQKV : [WQ;WK;WV] bf16, 6144x2048
//   [40,48M)  WOB  : wo bf16
//   [48,64M)  Q bf16 (token-major; RoPE'd + pre-scaled log2e/sqrt(128) by rope pass)
//   [64,80M)  K bf16 (token-major; RoPE'd)
//   [80,96M)  V^T bf16: [b*2048 + h*128 + d][s]

#define DMODEL 2048
#define SEQ    2048
#define NHEAD  16
#define DKH    128
#define NBATCH 2
#define MTOK   (NBATCH*SEQ)   // 4096

typedef float  f32x4  __attribute__((ext_vector_type(4)));
typedef __bf16 bf16x8 __attribute__((ext_vector_type(8)));
typedef unsigned short      u16;
typedef unsigned short      u16x4 __attribute__((ext_vector_type(4)));

#if __has_builtin(__builtin_amdgcn_exp2f)
#define EXP2F __builtin_amdgcn_exp2f
#else
#define EXP2F exp2f
#endif

__device__ __forceinline__ float b2f(u16 u) {
    union { unsigned i; float f; } x; x.i = ((unsigned)u) << 16; return x.f;
}
__device__ __forceinline__ u16 f2bf(float f) {  // round-to-nearest-even
    union { float f; unsigned i; } x; x.f = f;
    unsigned r = x.i + 0x7fffu + ((x.i >> 16) & 1u);
    return (u16)(r >> 16);
}

// async global->LDS, 16B per lane; LDS dest is wave-uniform base + lane*16
__device__ __forceinline__ void load_lds16(const void* g, void* l) {
    __builtin_amdgcn_global_load_lds(
        (const __attribute__((address_space(1))) void*)g,
        (__attribute__((address_space(3))) void*)l, 16, 0, 0);
}

// counted vmcnt wait; "memory" clobber pins LDS reads on the correct side
#define WAITVM(N) asm volatile("s_waitcnt vmcnt(" #N ")" ::: "memory")

// ---------------------------------------------------------------- fused casts
struct CastArgs {
    const float* src[5];
    u16*         dst[5];
    int          n4[5];
};
__global__ void cast_all_kernel(CastArgs a) {
    int j = blockIdx.y;
    int i = blockIdx.x * blockDim.x + threadIdx.x;
    if (i >= a.n4[j]) return;
    float4 f = ((const float4*)a.src[j])[i];
    uint2 o;
    o.x = (unsigned)f2bf(f.x) | ((unsigned)f2bf(f.y) << 16);
    o.y = (unsigned)f2bf(f.z) | ((unsigned)f2bf(f.w) << 16);
    ((uint2*)a.dst[j])[i] = o;
}

// ---------------------------------------------------------------- 2-phase pipelined GEMM
// Round-2 verified config (117 µs QKV / MfmaUtil 38%): 128x256 tile, BK=64,
// ring-3 LDS (144 KiB), 8 waves (2Mx4N) of 64x64, 2 phases/K-tile, counted
// vmcnt(6) once per K-tile (never drained to 0 in the loop).
//
// Phase = { 8x ds_read_b128 (pre-barrier) ; 3x global_load_lds ; s_barrier ;
//           lgkmcnt(0) ; sched_barrier ; setprio(1) ; 16 MFMA ; setprio(0) ;
//           s_barrier }.
// Ring-3 overwrite of slot (t+2)%3 == (t-1)%3 is safe: tile t-1's reads
// completed (lgkmcnt(0)+barrier) before stage(t+2) is issued.
//
// LDS swizzle: row r (stride 128B) stores k-chunk c at c ^ (r&7); inverse
// applied to the GLOBAL source address (global_load_lds writes linearly).
//
// MODE 0: QKV, grid 768. XCD x owns col-tiles [3x,3x+3) (W 3 MiB
//   L2-resident), sweeps rows col-fastest (FETCH evidence: 106 vs 209 MB).
// MODE 1: O-proj, grid 256 (1 block/CU). XCD x owns row-tiles [4x,4x+4).
template<int MODE>
__global__ __launch_bounds__(512, 2) void gemm_pipe(
    const u16* __restrict__ A, const u16* __restrict__ W,
    const float* __restrict__ qb, const float* __restrict__ kb,
    const float* __restrict__ vb,
    u16* __restrict__ QB, u16* __restrict__ KB, u16* __restrict__ VT,
    float* __restrict__ FO)
{
    constexpr int NT = 32;                  // 2048/64 K-tiles

    __shared__ __align__(16) u16 AS[3][128 * 64];   // 3 x 16 KiB
    __shared__ __align__(16) u16 BS[3][256 * 64];   // 3 x 32 KiB

    const int tid  = threadIdx.x;
    const int lane = tid & 63;
    const int w    = tid >> 6;               // 0..7
    const int wm   = w >> 2, wn = w & 3;     // 2 x 4 wave grid
    const int quad = lane >> 4, l16 = lane & 15;

    int row0, col0;
    if constexpr (MODE == 0) {
        int xcd = blockIdx.x & 7, loc = blockIdx.x >> 3;   // loc 0..95
        int rt  = loc / 3, cl = loc - rt * 3;
        row0 = rt * 128;
        col0 = (xcd * 3 + cl) * 256;
    } else {
        int xcd = blockIdx.x & 7, loc = blockIdx.x >> 3;   // loc 0..31
        row0 = (xcd * 4 + (loc & 3)) * 128;
        col0 = (loc >> 2) * 256;
    }

    const int rl = lane >> 3;                  // r & 7
    const int cg = (lane & 7) ^ rl;            // source chunk (inverse swizzle)

    f32x4 acc[4][4] = {};
    bf16x8 af[4], bfr[4];

#define STAGE_A(slot, j, k0)                                                       \
    load_lds16(A + (size_t)(row0 + (j) * 64 + w * 8 + rl) * 2048 + (k0) + cg * 8,  \
               (void*)((slot) + ((j) * 8 + w) * 512))
#define STAGE_B(slot, j, k0)                                                       \
    load_lds16(W + (size_t)(col0 + (j) * 64 + w * 8 + rl) * 2048 + (k0) + cg * 8,  \
               (void*)((slot) + ((j) * 8 + w) * 512))

#define DS_FRAGS(slotA, slotB, ks)                                          \
    {                                                                       \
        _Pragma("unroll") for (int mi = 0; mi < 4; ++mi) {                  \
            int r  = wm * 64 + mi * 16 + l16;                               \
            int cc = ((ks) * 4 + quad) ^ (r & 7);                           \
            af[mi] = *(const bf16x8*)((slotA) + r * 64 + cc * 8);           \
        }                                                                   \
        _Pragma("unroll") for (int ni = 0; ni < 4; ++ni) {                  \
            int r  = wn * 64 + ni * 16 + l16;                               \
            int cc = ((ks) * 4 + quad) ^ (r & 7);                           \
            bfr[ni] = *(const bf16x8*)((slotB) + r * 64 + cc * 8);          \
        }                                                                   \
    }

#define MFMA16()                                                            \
    __builtin_amdgcn_sched_barrier(0);                                      \
    __builtin_amdgcn_s_barrier();                                           \
    asm volatile("s_waitcnt lgkmcnt(0)" ::: "memory");                      \
    __builtin_amdgcn_sched_barrier(0);                                      \
    __builtin_amdgcn_s_setprio(1);                                          \
    _Pragma("unroll") for (int mi = 0; mi < 4; ++mi)                        \
        _Pragma("unroll") for (int ni = 0; ni < 4; ++ni)                    \
            acc[mi][ni] = __builtin_amdgcn_mfma_f32_16x16x32_bf16(          \
                af[mi], bfr[ni], acc[mi][ni], 0, 0, 0);                     \
    __builtin_amdgcn_s_setprio(0);                                          \
    __builtin_amdgcn_sched_barrier(0);                                      \
    __builtin_amdgcn_s_barrier();

    STAGE_A(AS[0], 0, 0);  STAGE_A(AS[0], 1, 0);
    STAGE_B(BS[0], 0, 0);  STAGE_B(BS[0], 1, 0);
    STAGE_B(BS[0], 2, 0);  STAGE_B(BS[0], 3, 0);
    STAGE_A(AS[1], 0, 64); STAGE_A(AS[1], 1, 64);
    STAGE_B(BS[1], 0, 64); STAGE_B(BS[1], 1, 64);
    STAGE_B(BS[1], 2, 64); STAGE_B(BS[1], 3, 64);
    WAITVM(6);
    __builtin_amdgcn_s_barrier();

    int sC = 0, sS = 2;
    for (int t = 0; t < NT - 2; ++t) {
        u16* Ac  = AS[sC]; u16* Bc  = BS[sC];
        u16* Asg = AS[sS]; u16* Bsg = BS[sS];
        const int k0s = (t + 2) * 64;
        DS_FRAGS(Ac, Bc, 0);
        STAGE_A(Asg, 0, k0s); STAGE_A(Asg, 1, k0s); STAGE_B(Bsg, 0, k0s);
        MFMA16();
        DS_FRAGS(Ac, Bc, 1);
        STAGE_B(Bsg, 1, k0s); STAGE_B(Bsg, 2, k0s); STAGE_B(Bsg, 3, k0s);
        WAITVM(6);
        MFMA16();
        sC = (sC == 2) ? 0 : sC + 1;
        sS = (sS == 2) ? 0 : sS + 1;
    }
    {   // t = NT-2
        u16* Ac = AS[sC]; u16* Bc = BS[sC];
        DS_FRAGS(Ac, Bc, 0); MFMA16();
        DS_FRAGS(Ac, Bc, 1); WAITVM(0); MFMA16();
        sC = (sC == 2) ? 0 : sC + 1;
    }
    {   // t = NT-1
        u16* Ac = AS[sC]; u16* Bc = BS[sC];
        DS_FRAGS(Ac, Bc, 0); MFMA16();
        DS_FRAGS(Ac, Bc, 1);
        asm volatile("s_waitcnt lgkmcnt(0)" ::: "memory");
        __builtin_amdgcn_sched_barrier(0);
#pragma unroll
        for (int mi = 0; mi < 4; ++mi)
#pragma unroll
            for (int ni = 0; ni < 4; ++ni)
                acc[mi][ni] = __builtin_amdgcn_mfma_f32_16x16x32_bf16(
                    af[mi], bfr[ni], acc[mi][ni], 0, 0, 0);
    }

    // ---------------- epilogue ----------------
    if constexpr (MODE == 1) {
#pragma unroll
        for (int mi = 0; mi < 4; ++mi) {
#pragma unroll
            for (int ni = 0; ni < 4; ++ni) {
                int col = col0 + wn * 64 + ni * 16 + l16;
                float bv = qb[col];   // wo_b
#pragma unroll
                for (int r = 0; r < 4; ++r) {
                    int row = row0 + wm * 64 + mi * 16 + quad * 4 + r;
                    FO[(size_t)row * DMODEL + col] = acc[mi][ni][r] + bv;
                }
            }
        }
    } else {
        const int sect = col0 >> 11;   // 0=Q, 1=K, 2=V
        if (sect == 2) {
            // V^T epilogue: s consecutive over reg index -> u16x4 store
#pragma unroll
            for (int mi = 0; mi < 4; ++mi) {
#pragma unroll
                for (int ni = 0; ni < 4; ++ni) {
                    int colv = (col0 & 2047) + wn * 64 + ni * 16 + l16;
                    float bv = vb[colv];
                    int rowb = row0 + wm * 64 + mi * 16 + quad * 4;
                    int bb = rowb >> 11, s = rowb & 2047;
                    u16x4 pk;
#pragma unroll
                    for (int r = 0; r < 4; ++r) pk[r] = f2bf(acc[mi][ni][r] + bv);
                    *(u16x4*)(VT + (size_t)(bb * 2048 + colv) * 2048 + s) = pk;
                }
            }
        } else {
            const float* bias = sect ? kb : qb;
            u16* dst          = sect ? KB : QB;
#pragma unroll
            for (int mi = 0; mi < 4; ++mi) {
#pragma unroll
                for (int ni = 0; ni < 4; ++ni) {
                    int col = (col0 & 2047) + wn * 64 + ni * 16 + l16;
                    float bv = bias[col];
#pragma unroll
                    for (int r = 0; r < 4; ++r) {
                        int row = row0 + wm * 64 + mi * 16 + quad * 4 + r;
                        dst[(size_t)row * 2048 + col] = f2bf(acc[mi][ni][r] + bv);
                    }
                }
            }
        }
    }
#undef STAGE_A
#undef STAGE_B
#undef DS_FRAGS
#undef MFMA16
}

// ---------------------------------------------------------------- RoPE (in-place, table-in-LDS)
// One block per token (b,s). The old kernel evaluated sincosf 8.4M times
// (per (b,s,h,i,Q/K)) with large-angle libm range reduction -> VALU-bound
// (m205 trap). Only 2048x64 unique angles exist: compute the 64 angles for
// this token once into LDS (262K sincos total, 32x fewer), then stream the
// Q and K rows with uint4 (16B/lane) coalesced accesses.
// Per-pair math identical to before: Q gets *log2e/sqrt(128), K unscaled.
__global__ __launch_bounds__(256) void rope_kernel(u16* __restrict__ Q, u16* __restrict__ Kt) {
    const int tok = blockIdx.x;              // b*2048 + s  (row index)
    const int s   = tok & (SEQ - 1);
    const int tid = threadIdx.x;

    __shared__ float cs[64], sn[64];
    if (tid < 64) {
        float inv_freq = exp2f(-13.287712379549449f * (float)tid * (1.0f / 64.0f));
        float c, n;
        sincosf((float)s * inv_freq, &n, &c);
        cs[tid] = c; sn[tid] = n;
    }
    __syncthreads();

    const int i0 = (tid * 4) & 63;           // pair p = tid*4+k  ->  i = p & 63
#pragma unroll
    for (int qk = 0; qk < 2; ++qk) {
        u16* P      = qk ? Kt : Q;
        float scale = qk ? 1.0f : 0.12751743558f;   // log2e/sqrt(128) on Q
        uint4* row  = (uint4*)(P + (size_t)tok * 2048);
        uint4 v = row[tid];
        unsigned vv[4] = { v.x, v.y, v.z, v.w };
        unsigned res[4];
#pragma unroll
        for (int k = 0; k < 4; ++k) {
            int i = (i0 + k) & 63;
            float e = b2f((u16)(vv[k] & 0xffff)), o = b2f((u16)(vv[k] >> 16));
            float re = (e * cs[i] - o * sn[i]) * scale;
            float ro = (e * sn[i] + o * cs[i]) * scale;
            res[k] = (unsigned)f2bf(re) | ((unsigned)f2bf(ro) << 16);
        }
        row[tid] = make_uint4(res[0], res[1], res[2], res[3]);
    }
}

// ---------------------------------------------------------------- flash attention
// Round-0/2 proven version. Paired-tile blocks (waves 0-3: q-tile p, waves
// 4-7: q-tile 31-p) sharing staged K/V^T. Constant-max exp2 softmax:
// p = exp2(s - 32); the 2^-32 shift is exact and undone by the final 1/l.
// l-sum reduced across lanes ONCE after the K-loop.
__global__ __launch_bounds__(512, 4) void attn_kernel(
    const u16* __restrict__ Q, const u16* __restrict__ Kg,
    const u16* __restrict__ VTg, u16* __restrict__ Out)
{
    const int p  = blockIdx.x;           // pair index 0..15
    const int bh = blockIdx.y;
    const int b  = bh >> 4, h = bh & 15;

    const int tid  = threadIdx.x;
    const int lane = tid & 63;
    const int w    = tid >> 6;           // 0..7
    const int half = w >> 2;             // 0 = low tile, 1 = high tile
    const int wsub = w & 3;
    const int quad = lane >> 4, l16 = lane & 15;

    const int q_hi  = 31 - p;
    const int my_qt = half ? q_hi : p;
    const int q0    = my_qt * 64;

    __shared__ u16 Ks[64 * 128];         // 16 KB, swizzle ^(r&15)
    __shared__ u16 Vt[128 * 64];         // 16 KB, [d][key], swizzle ^(r&7)
    __shared__ u16 Ps[8][16 * 72];       // 18 KB per-wave P buffers

    bf16x8 qf[4];
    const u16* qrow = Q + (size_t)(b * SEQ + q0 + wsub * 16 + l16) * DMODEL + h * DKH;
#pragma unroll
    for (int ks = 0; ks < 4; ++ks) qf[ks] = *(const bf16x8*)(qrow + ks * 32 + quad * 8);

    f32x4 o[8] = {};
    float l_r[4] = { 0.f, 0.f, 0.f, 0.f };   // per-lane partial softmax sums

    for (int kt = 0; kt <= q_hi; ++kt) {
        const int k0 = kt * 64;
        // ---- stage K (1024 chunks, 512 threads -> 2 each)
#pragma unroll
        for (int i = 0; i < 2; ++i) {
            int cb = (i * 8 + w) * 64;
            int pc = cb + lane;
            int r  = pc >> 4;
            int cl = (pc & 15) ^ (r & 15);
            load_lds16(Kg + (size_t)(b * SEQ + k0 + r) * DMODEL + h * DKH + cl * 8,
                       (void*)(Ks + cb * 8));
        }
        // ---- stage V^T
#pragma unroll
        for (int i = 0; i < 2; ++i) {
            int cb = (i * 8 + w) * 64;
            int pc = cb + lane;
            int r  = pc >> 3;                 // d
            int cl = (pc & 7) ^ (r & 7);
            load_lds16(VTg + (size_t)(b * 2048 + h * DKH + r) * SEQ + k0 + cl * 8,
                       (void*)(Vt + cb * 8));
        }
        __syncthreads();

        if (kt <= my_qt) {
            // ---- S = Q K^T  (exp2-domain: log2e*scale folded into Q)
            f32x4 sc[4] = {};
#pragma unroll
            for (int ks = 0; ks < 4; ++ks) {
#pragma unroll
                for (int nt = 0; nt < 4; ++nt) {
                    int r  = nt * 16 + l16;
                    int pc = (ks * 4 + quad) ^ (r & 15);
                    bf16x8 kf = *(const bf16x8*)(Ks + (r * 16 + pc) * 8);
                    sc[nt] = __builtin_amdgcn_mfma_f32_16x16x32_bf16(qf[ks], kf, sc[nt], 0, 0, 0);
                }
            }
            if (kt == my_qt) {
#pragma unroll
                for (int nt = 0; nt < 4; ++nt)
#pragma unroll
                    for (int r = 0; r < 4; ++r) {
                        int col = k0 + nt * 16 + l16;
                        int row = q0 + wsub * 16 + quad * 4 + r;
                        if (col > row) sc[nt][r] = -1e30f;
                    }
            }
            // ---- p = exp2(s - 32); accumulate per-lane l; store P to LDS
#pragma unroll
            for (int nt = 0; nt < 4; ++nt)
#pragma unroll
                for (int r = 0; r < 4; ++r) {
                    float pv = EXP2F(sc[nt][r] - 32.0f);
                    l_r[r] += pv;
                    Ps[w][(quad * 4 + r) * 72 + nt * 16 + l16] = f2bf(pv);
                }
            // ---- O += P V  (same-wave LDS write->read; no barrier needed)
#pragma unroll
            for (int ks = 0; ks < 2; ++ks) {
                bf16x8 pf = *(const bf16x8*)(&Ps[w][l16 * 72 + ks * 32 + quad * 8]);
#pragma unroll
                for (int nt = 0; nt < 8; ++nt) {
                    int r  = nt * 16 + l16;                  // d
                    int pc = (ks * 4 + quad) ^ (r & 7);
                    bf16x8 vf = *(const bf16x8*)(Vt + r * 64 + pc * 8);
                    o[nt] = __builtin_amdgcn_mfma_f32_16x16x32_bf16(pf, vf, o[nt], 0, 0, 0);
                }
            }
        }
        __syncthreads();
    }

    // ---- one l-reduction across the 16 lanes of each quad, then store
#pragma unroll
    for (int r = 0; r < 4; ++r) {
#pragma unroll
        for (int off = 1; off < 16; off <<= 1) l_r[r] += __shfl_xor(l_r[r], off);
        float inv = 1.0f / l_r[r];
        int row = q0 + wsub * 16 + quad * 4 + r;
#pragma unroll
        for (int nt = 0; nt < 8; ++nt)
            Out[(size_t)(b * SEQ + row) * DMODEL + h * DKH + nt * 16 + l16] = f2bf(o[nt][r] * inv);
    }
}

// ---------------------------------------------------------------- launch
extern "C" void kernel_launch(void* const* d_in, const int* in_sizes, int n_in,
                              void* d_out, int out_size, void* d_ws, size_t ws_size,
                              hipStream_t stream)
{
    const float* x    = (const float*)d_in[0];
    const float* wq_w = (const float*)d_in[1];
    const float* wq_b = (const float*)d_in[2];
    const float* wk_w = (const float*)d_in[3];
    const float* wk_b = (const float*)d_in[4];
    const float* wv_w = (const float*)d_in[5];
    const float* wv_b = (const float*)d_in[6];
    const float* wo_w = (const float*)d_in[7];
    const float* wo_b = (const float*)d_in[8];
    float* out = (float*)d_out;

    char* ws = (char*)d_ws;
    u16* XB   = (u16*)(ws);                     // 16 MiB, reused as attn output
    u16* WQKV = (u16*)(ws + (16u << 20));       // 24 MiB
    u16* WOB  = (u16*)(ws + (40u << 20));       // 8 MiB
    u16* QB   = (u16*)(ws + (48u << 20));
    u16* KB   = (u16*)(ws + (64u << 20));
    u16* VTB  = (u16*)(ws + (80u << 20));       // V^T: [b*2048+h*128+d][s]

    CastArgs ca;
    ca.src[0] = x;    ca.dst[0] = XB;                         ca.n4[0] = (MTOK * DMODEL) / 4;
    ca.src[1] = wq_w; ca.dst[1] = WQKV;                       ca.n4[1] = (DMODEL * DMODEL) / 4;
    ca.src[2] = wk_w; ca.dst[2] = WQKV + DMODEL * DMODEL;     ca.n4[2] = (DMODEL * DMODEL) / 4;
    ca.src[3] = wv_w; ca.dst[3] = WQKV + 2 * DMODEL * DMODEL; ca.n4[3] = (DMODEL * DMODEL) / 4;
    ca.src[4] = wo_w; ca.dst[4] = WOB;                        ca.n4[4] = (DMODEL * DMODEL) / 4;
    cast_all_kernel<<<dim3(8192, 5), 256, 0, stream>>>(ca);

    // QKV: 32 row-tiles x 24 col-tiles = 768 blocks (3 full CU rounds)
    gemm_pipe<0><<<dim3(768), 512, 0, stream>>>(
        XB, WQKV, wq_b, wk_b, wv_b, QB, KB, VTB, nullptr);

    // RoPE: one block per token; 64 sincos -> LDS, uint4 row streaming
    rope_kernel<<<dim3(MTOK), 256, 0, stream>>>(QB, KB);

    attn_kernel<<<dim3(16, NBATCH * NHEAD), 512, 0, stream>>>(QB, KB, VTB, XB);

    // O-proj: 32 x 8 = 256 blocks (exactly 1/CU)
    gemm_pipe<1><<<dim3(256), 512, 0, stream>>>(
        XB, WOB, wo_b, nullptr, nullptr, nullptr, nullptr, nullptr, out);
}